// Round 10
// baseline (1690.679 us; speedup 1.0000x reference)
//
#include <hip/hip_runtime.h>
#include <hip/hip_bf16.h>

// GroupedExperts: out[t] = (silu(x@w1[e]^T) * (x@w3[e]^T)) @ w2[e]^T
// E=8, T=16384, D=2048, H=5632; tokens pre-sorted by expert, even split.
//
// Round 10: 2 blocks/CU TLP. 4-wave blocks (256 thr, 2Mx2N), block tile
// 256x128, wave tile 128x64 (read-optimal), BK=32, ring-3 LDS (72KB ->
// 2 blocks/CU co-resident = two independent barrier domains; block A's
// MFMA overlaps block B's LDS phases). ONE barrier + ONE counted vmcnt(6)
// per K32-tile; reads consume data staged 2 tiles earlier (ledger
// verified). Swizzle q^=(row>>1)&3 on 64B rows + per-lane-constant
// inverse on staging source (R5/R6-proven). Fused w2 f32->bf16 cvt in
// gate_up prologue; expert-per-XCD cluster mapping (tn-fastest).

typedef __bf16 bf16x8 __attribute__((ext_vector_type(8)));
typedef float f32x4 __attribute__((ext_vector_type(4)));
typedef unsigned short u16x8 __attribute__((ext_vector_type(8)));

constexpr int E = 8;
constexpr int T = 16384;
constexpr int D = 2048;
constexpr int H = 5632;

#define DEV static __device__ __forceinline__

DEV unsigned short f2bf(float f) {
    unsigned u = __builtin_bit_cast(unsigned, f);
    u = (u + 0x7FFFu + ((u >> 16) & 1u)) >> 16;   // RNE
    return (unsigned short)u;
}

DEV void gload16(const void* g, void* l) {
    __builtin_amdgcn_global_load_lds(
        (const __attribute__((address_space(1))) void*)g,
        (__attribute__((address_space(3))) void*)l, 16, 0, 0);
}

DEV f32x4 mfma16(bf16x8 a, bf16x8 b, f32x4 c) {
    return __builtin_amdgcn_mfma_f32_16x16x32_bf16(a, b, c, 0, 0, 0);
}

DEV void cvt8(const float* src, unsigned short* dst) {
    float4 a = *(const float4*)src;
    float4 c = *(const float4*)(src + 4);
    u16x8 r;
    r[0] = f2bf(a.x); r[1] = f2bf(a.y); r[2] = f2bf(a.z); r[3] = f2bf(a.w);
    r[4] = f2bf(c.x); r[5] = f2bf(c.y); r[6] = f2bf(c.z); r[7] = f2bf(c.w);
    *(u16x8*)dst = r;
}

DEV void SB() { __builtin_amdgcn_sched_barrier(0); }

// ------- merged pre-GEMM converts: x (linear) + w1/w3 (interleave-16) -----
// w13b[e] row layout: rr = (h>>4)*32 + which*16 + (h&15); which 0=w1, 1=w3.
__global__ __launch_bounds__(256) void k_cvt_pre(
    const float* __restrict__ x, const float* __restrict__ w1,
    const float* __restrict__ w3, unsigned short* __restrict__ xb,
    unsigned short* __restrict__ w13b) {
    const int bid = blockIdx.x, tid = threadIdx.x;
    if (bid < 512) {
        const long n8 = (long)T * D / 8;
        for (long i = (long)bid * 256 + tid; i < n8; i += 512L * 256)
            cvt8(x + i * 8, xb + i * 8);
    } else {
        const int which = (bid < 1280) ? 0 : 1;
        const float* src = which ? w3 : w1;
        const long b0 = which ? 1280 : 512;
        const long n8 = (long)E * H * D / 8;
        for (long i = ((long)bid - b0) * 256 + tid; i < n8; i += 768L * 256) {
            int col8 = (int)(i & 255);          // D/8 = 256
            int rowi = (int)(i >> 8);           // e*H + h
            int e = rowi / H;
            int h = rowi - e * H;
            int rr = ((h >> 4) << 5) + (which << 4) + (h & 15);
            cvt8(src + i * 8,
                 w13b + ((size_t)e * (2 * H) + rr) * D + (size_t)col8 * 8);
        }
    }
}

// linear cvt (w2 fallback when ws too small for the fused path)
__global__ __launch_bounds__(256) void k_cvt(const float* __restrict__ in,
                                             unsigned short* __restrict__ out,
                                             long n8) {
    long i = (long)blockIdx.x * blockDim.x + threadIdx.x;
    long stride = (long)gridDim.x * blockDim.x;
    for (; i < n8; i += stride) cvt8(in + i * 8, out + i * 8);
}

// ---------------- expert lookup for a row tile ----------------------------
DEV int expert_of_row(const int* __restrict__ ntp, int row0) {
    int e = 0, s = 0;
    for (int i = 0; i < E; ++i) {
        int c = ntp[i];
        if (row0 < s + c) { e = i; break; }
        s += c;
    }
    return e;
}

// ---------------- 256x128 BK=32 ring-3 GEMM core (4 waves) ----------------
// 256 thr = 4 waves (2M x 2N); wave out 128x64 = acc[8][4] f32x4.
// LDS: sA = 3 slots x 16KB (256x32), sB = 3 slots x 8KB (128x32) = 72KB.
// Swizzle: 16B quarter q of row r stored at q ^ ((r>>1)&3); staging source
// pre-applies inverse (per-lane const (l&3)^((l>>3)&3)); linear gload dest.
// Per tile t: p0{rd A m0-3 + B n0-3 (8); stage A(t+2); lgkm0; 16 MFMA}
//             p1{rd A m4-7 (4); stage B(t+2); lgkm0; 16 MFMA; vmcnt(6);
//                barrier}
// Tile-t data staged at t-2, retired by each wave's vmcnt(6) at t-1,
// published by barrier(t-1). Slot overwritten at t held t-1's data whose
// readers finished before barrier(t-1). One barrier/tile total.
template <int LD, int NT>
DEV void gemm_r3(const unsigned short* pa, const unsigned short* pb,
                 unsigned short* sA, unsigned short* sB, int tid,
                 f32x4 (&acc)[8][4]) {
    const int lane = tid & 63, wid = tid >> 6;
    const int wm = wid >> 1, wn = wid & 1;

    const int q8 = (((lane >> 4) ^ ((lane >> 1) & 3)) << 3);
    const int aoff = (wm * 128 + (lane & 15)) * 32 + q8;
    const int boff = (wn * 64 + (lane & 15)) * 32 + q8;

    char* cA = (char*)sA;
    char* cB = (char*)sB;
    const int dA = wid << 12;   // wave A stage region: 4KB
    const int dB = wid << 11;   // wave B stage region: 2KB

    auto stA = [&](int t, int slot) {
        const unsigned short* g = pa + (size_t)t * 32;
        char* l = cA + slot * 16384 + dA;
#pragma unroll
        for (int i = 0; i < 4; ++i)
            gload16(g + (size_t)i * 16 * LD, l + i * 1024);
    };
    auto stB = [&](int t, int slot) {
        const unsigned short* g = pb + (size_t)t * 32;
        char* l = cB + slot * 8192 + dB;
#pragma unroll
        for (int i = 0; i < 2; ++i)
            gload16(g + (size_t)i * 16 * LD, l + i * 1024);
    };

    // prologue: tiles 0,1 -> slots 0,1; retire tile 0 (6 loads stay)
    stA(0, 0); stB(0, 0);
    stA(1, 1); stB(1, 1);
    asm volatile("s_waitcnt vmcnt(6)" ::: "memory");
    __builtin_amdgcn_s_barrier();

    int scur = 0, sstg = 2;
#pragma unroll 1
    for (int t = 0; t < NT; ++t) {
        const unsigned short* A = sA + scur * 8192 + aoff;
        const unsigned short* B = sB + scur * 4096 + boff;
        const bool s2 = (t + 2 < NT);
        bf16x8 a[4], b[4];

        // ===== p0: A m0-3 + B n0-3; stage A(t+2); MFMA m0-3 x n0-3 =====
#pragma unroll
        for (int i = 0; i < 4; ++i) a[i] = *(const bf16x8*)(A + i * 512);
#pragma unroll
        for (int i = 0; i < 4; ++i) b[i] = *(const bf16x8*)(B + i * 512);
        if (s2) stA(t + 2, sstg);
        asm volatile("s_waitcnt lgkmcnt(0)" ::: "memory");
        SB();
        __builtin_amdgcn_s_setprio(1);
#pragma unroll
        for (int m = 0; m < 4; ++m)
#pragma unroll
            for (int n = 0; n < 4; ++n)
                acc[m][n] = mfma16(a[m], b[n], acc[m][n]);
        __builtin_amdgcn_s_setprio(0);

        // ===== p1: A m4-7; stage B(t+2); MFMA m4-7 x n0-3 =====
#pragma unroll
        for (int i = 0; i < 4; ++i)
            a[i] = *(const bf16x8*)(A + 2048 + i * 512);
        if (s2) stB(t + 2, sstg);
        asm volatile("s_waitcnt lgkmcnt(0)" ::: "memory");
        SB();
        __builtin_amdgcn_s_setprio(1);
#pragma unroll
        for (int m = 0; m < 4; ++m)
#pragma unroll
            for (int n = 0; n < 4; ++n)
                acc[4 + m][n] = mfma16(a[m], b[n], acc[4 + m][n]);
        __builtin_amdgcn_s_setprio(0);

        if (s2)               asm volatile("s_waitcnt vmcnt(6)" ::: "memory");
        else if (t + 1 < NT)  asm volatile("s_waitcnt vmcnt(0)" ::: "memory");
        __builtin_amdgcn_s_barrier();
        SB();

        sstg = scur;
        scur = (scur == 2) ? 0 : scur + 1;
    }
}

// ---------------- kernel 1: fused gate/up grouped GEMM + SwiGLU -----------
// A = xb (T x D), B = w13b[e] (2H x D interleave-16), h (T x H bf16).
// Grid 64tm x 88tn = 5632; expert-per-XCD, tn-fastest (A L2-resident).
__global__ __launch_bounds__(256, 2) void k_gate_up(
    const unsigned short* __restrict__ xb,
    const unsigned short* __restrict__ w13b,
    const float* __restrict__ w2, unsigned short* __restrict__ w2b,
    const int* __restrict__ ntp, unsigned short* __restrict__ hbuf) {
    __shared__ unsigned short sA[3 * 8192];
    __shared__ unsigned short sB[3 * 4096];

    const int bid = blockIdx.x;
    const int tid = threadIdx.x;

    if (w2) {  // fused w2 convert: 16384 elems/block, then drain vmcnt
        const float* src = w2 + (size_t)bid * 16384;
        unsigned short* dst = w2b + (size_t)bid * 16384;
#pragma unroll
        for (int it = 0; it < 8; ++it) {
            int o = (it * 256 + tid) * 8;
            cvt8(src + o, dst + o);
        }
        asm volatile("s_waitcnt vmcnt(0)" ::: "memory");
    }

    // expert-per-XCD cluster: XCD x owns tm in [x*8, x*8+8) = expert x.
    const int xcd = bid & 7;
    const int j = bid >> 3;              // 0..703
    const int tn = j % 88;
    const int tm = xcd * 8 + j / 88;     // 0..63

    const int row0 = tm << 8;
    const int e = expert_of_row(ntp, row0);
    const int lane = tid & 63, wid = tid >> 6;

    // staging sources (inverse-swizzled k-quarter, per-lane constant)
    const int sq = (lane & 3) ^ ((lane >> 3) & 3);
    const int ar = (wid << 6) + (lane >> 2);        // A row 0..255
    const int br = (wid << 5) + (lane >> 2);        // B row 0..127
    const unsigned short* pa = xb + (size_t)(row0 + ar) * D + sq * 8;
    const unsigned short* pb = w13b + (size_t)e * (2 * H) * D +
                               (size_t)((tn << 7) + br) * D + sq * 8;

    f32x4 acc[8][4] = {};
    gemm_r3<D, D / 32>(pa, pb, sA, sB, tid, acc);

    // Epilogue: ni pairs (0,1),(2,3) = (gate,up). C/D: col=lane&15,
    // row=(lane>>4)*4+j. h col group = tn*4 + wn*2 + pi.
    const int wm = wid >> 1, wn = wid & 1;
    const int rbase = row0 + (wm << 7) + ((lane >> 4) << 2);
    const int cb = (((tn << 2) + (wn << 1)) << 4) + (lane & 15);
#pragma unroll
    for (int mi = 0; mi < 8; ++mi)
#pragma unroll
        for (int pi = 0; pi < 2; ++pi) {
            f32x4 g = acc[mi][2 * pi], u = acc[mi][2 * pi + 1];
            const int hcol = cb + (pi << 4);
#pragma unroll
            for (int jj = 0; jj < 4; ++jj) {
                float gv = g[jj];
                float hv = gv * u[jj] / (1.f + __expf(-gv));
                hbuf[(size_t)(rbase + (mi << 4) + jj) * H + hcol] = f2bf(hv);
            }
        }
}

// ---------------- kernel 2: down grouped GEMM -----------------------------
// A = h (T x H), B = w2b[e] (D x H), out (T x D f32). K = H = 5632.
// Grid 64tm x 16tn = 1024; expert-per-XCD.
__global__ __launch_bounds__(256, 2) void k_down(
    const unsigned short* __restrict__ hbuf,
    const unsigned short* __restrict__ w2b,
    const int* __restrict__ ntp,
    float* __restrict__ out) {
    __shared__ unsigned short sA[3 * 8192];
    __shared__ unsigned short sB[3 * 4096];

    const int bid = blockIdx.x;
    const int tid = threadIdx.x;
    const int xcd = bid & 7;
    const int j = bid >> 3;              // 0..127
    const int tn = j & 15;
    const int tm = xcd * 8 + (j >> 4);   // 0..63

    const int row0 = tm << 8;
    const int e = expert_of_row(ntp, row0);
    const int lane = tid & 63, wid = tid >> 6;

    const int sq = (lane & 3) ^ ((lane >> 3) & 3);
    const int ar = (wid << 6) + (lane >> 2);
    const int br = (wid << 5) + (lane >> 2);
    const unsigned short* pa = hbuf + (size_t)(row0 + ar) * H + sq * 8;
    const unsigned short* pb = w2b + (size_t)e * D * H +
                               (size_t)((tn << 7) + br) * H + sq * 8;

    f32x4 acc[8][4] = {};
    gemm_r3<H, H / 32>(pa, pb, sA, sB, tid, acc);

    const int wm = wid >> 1, wn = wid & 1;
    const int rbase = row0 + (wm << 7) + ((lane >> 4) << 2);
    const int cb = (tn << 7) + (wn << 6) + (lane & 15);
#pragma unroll
    for (int mi = 0; mi < 8; ++mi)
#pragma unroll
        for (int ni = 0; ni < 4; ++ni) {
            f32x4 c = acc[mi][ni];
#pragma unroll
            for (int jj = 0; jj < 4; ++jj)
                out[(size_t)(rbase + (mi << 4) + jj) * D + cb + (ni << 4)] =
                    c[jj];
        }
}

extern "C" void kernel_launch(void* const* d_in, const int* in_sizes, int n_in,
                              void* d_out, int out_size, void* d_ws,
                              size_t ws_size, hipStream_t stream) {
    const float* x = (const float*)d_in[0];
    const float* w1 = (const float*)d_in[1];
    const float* w2 = (const float*)d_in[2];
    const float* w3 = (const float*)d_in[3];
    const int* ntp = (const int*)d_in[4];
    float* out = (float*)d_out;

    char* ws = (char*)d_ws;
    // ws layout (bytes):
    //   xb  : [0, 67108864)                       T*D*2
    //   w13b: [67108864, 436207616)               E*2H*D*2
    //   h   : [436207616, 620756992)              T*H*2
    //   w2b : [620756992, 805306368)  if ws fits  E*D*H*2 (else alias w13b)
    unsigned short* xb = (unsigned short*)(ws + 0);
    unsigned short* w13b = (unsigned short*)(ws + 67108864L);
    unsigned short* hbuf = (unsigned short*)(ws + 436207616L);
    const bool big = ws_size >= 805306368UL;
    unsigned short* w2b = big ? (unsigned short*)(ws + 620756992L) : w13b;

    k_cvt_pre<<<2048, 256, 0, stream>>>(x, w1, w3, xb, w13b);

    k_gate_up<<<(T / 256) * (2 * H / 128), 256, 0, stream>>>(
        xb, w13b, big ? w2 : nullptr, big ? w2b : nullptr, ntp, hbuf);

    if (!big)
        k_cvt<<<2048, 256, 0, stream>>>(w2, w2b, (long)E * D * H / 8);

    k_down<<<(T / 256) * (D / 128), 256, 0, stream>>>(hbuf, w2b, ntp, out);
}

// Round 11
// 1393.586 us; speedup vs baseline: 1.2132x; 1.2132x over previous
//
#include <hip/hip_runtime.h>
#include <hip/hip_bf16.h>

// GroupedExperts: out[t] = (silu(x@w1[e]^T) * (x@w3[e]^T)) @ w2[e]^T
// E=8, T=16384, D=2048, H=5632; tokens pre-sorted by expert, even split.
//
// Round 11: R9 (best, 1416us) with ONE change: k_down gets the
// expert-per-XCD cluster mapping (XCD x owns tm in [8x,8x+8) = expert x,
// tn in [0,8)). R9's strip mapping made every XCD stream ALL of h through
// its L2 (A fetched ~8x ~= 1.5 GB); cluster makes A and B single-fetch
// (slice working set ~512KB << 4MB L2). Same mechanism that cut gate_up
// FETCH 1.62GB -> 721MB. Everything else byte-identical to R9.

typedef __bf16 bf16x8 __attribute__((ext_vector_type(8)));
typedef float f32x4 __attribute__((ext_vector_type(4)));
typedef unsigned short u16x8 __attribute__((ext_vector_type(8)));

constexpr int E = 8;
constexpr int T = 16384;
constexpr int D = 2048;
constexpr int H = 5632;

#define DEV static __device__ __forceinline__

DEV unsigned short f2bf(float f) {
    unsigned u = __builtin_bit_cast(unsigned, f);
    u = (u + 0x7FFFu + ((u >> 16) & 1u)) >> 16;   // RNE
    return (unsigned short)u;
}

DEV void gload16(const void* g, void* l) {
    __builtin_amdgcn_global_load_lds(
        (const __attribute__((address_space(1))) void*)g,
        (__attribute__((address_space(3))) void*)l, 16, 0, 0);
}

DEV f32x4 mfma16(bf16x8 a, bf16x8 b, f32x4 c) {
    return __builtin_amdgcn_mfma_f32_16x16x32_bf16(a, b, c, 0, 0, 0);
}

DEV void cvt8(const float* src, unsigned short* dst) {
    float4 a = *(const float4*)src;
    float4 c = *(const float4*)(src + 4);
    u16x8 r;
    r[0] = f2bf(a.x); r[1] = f2bf(a.y); r[2] = f2bf(a.z); r[3] = f2bf(a.w);
    r[4] = f2bf(c.x); r[5] = f2bf(c.y); r[6] = f2bf(c.z); r[7] = f2bf(c.w);
    *(u16x8*)dst = r;
}

// ------- merged pre-GEMM converts: x (linear) + w1/w3 (interleave-16) -----
// w13b[e] row layout: rr = (h>>4)*32 + which*16 + (h&15); which 0=w1, 1=w3.
__global__ __launch_bounds__(256) void k_cvt_pre(
    const float* __restrict__ x, const float* __restrict__ w1,
    const float* __restrict__ w3, unsigned short* __restrict__ xb,
    unsigned short* __restrict__ w13b) {
    const int bid = blockIdx.x, tid = threadIdx.x;
    if (bid < 512) {
        const long n8 = (long)T * D / 8;
        for (long i = (long)bid * 256 + tid; i < n8; i += 512L * 256)
            cvt8(x + i * 8, xb + i * 8);
    } else {
        const int which = (bid < 1280) ? 0 : 1;
        const float* src = which ? w3 : w1;
        const long b0 = which ? 1280 : 512;
        const long n8 = (long)E * H * D / 8;
        for (long i = ((long)bid - b0) * 256 + tid; i < n8; i += 768L * 256) {
            int col8 = (int)(i & 255);          // D/8 = 256
            int rowi = (int)(i >> 8);           // e*H + h
            int e = rowi / H;
            int h = rowi - e * H;
            int rr = ((h >> 4) << 5) + (which << 4) + (h & 15);
            cvt8(src + i * 8,
                 w13b + ((size_t)e * (2 * H) + rr) * D + (size_t)col8 * 8);
        }
    }
}

// linear cvt (w2 fallback when ws too small for the fused path)
__global__ __launch_bounds__(256) void k_cvt(const float* __restrict__ in,
                                             unsigned short* __restrict__ out,
                                             long n8) {
    long i = (long)blockIdx.x * blockDim.x + threadIdx.x;
    long stride = (long)gridDim.x * blockDim.x;
    for (; i < n8; i += stride) cvt8(in + i * 8, out + i * 8);
}

// ---------------- expert lookup for a row tile ----------------------------
DEV int expert_of_row(const int* __restrict__ ntp, int row0) {
    int e = 0, s = 0;
    for (int i = 0; i < E; ++i) {
        int c = ntp[i];
        if (row0 < s + c) { e = i; break; }
        s += c;
    }
    return e;
}

// ---------------- 256x256 BK=64 4-phase GEMM core (R6 verbatim) -----------
// 512 thr = 8 waves (2M x 4N); wave out 128x64 = acc[8][4] f32x4.
// LDS per operand: 2 buf x 2 kk-slice x (256 rows x 32 el, 64B rows) = 64KB.
// Swizzle: 16B quarter q of row r stored at q ^ ((r>>1)&3).
// Phases (16 MFMA each): p0 rd{A m0-3 kk0, B kk0} st A-kk0(t+1)
//                        p1 rd{A m4-7 kk0}        st B-kk0(t+1) vm4
//                        p2 rd{A m0-3 kk1, B kk1} st A-kk1(t+1)
//                        p3 rd{A m4-7 kk1}        st B-kk1(t+1) vm4
template <int LD, int NT>
DEV void gemm_4p(const unsigned short* pa, const unsigned short* pb,
                 unsigned short* sA, unsigned short* sB, int tid,
                 f32x4 (&acc)[8][4]) {
    const int lane = tid & 63, wid = tid >> 6;
    const int wm = wid >> 2, wn = wid & 3;

    const int q8 = (((lane >> 4) ^ ((lane >> 1) & 3)) << 3);
    const int aoff = (wm * 128 + (lane & 15)) * 32 + q8;
    const int boff = (wn * 64 + (lane & 15)) * 32 + q8;

    char* lA = (char*)sA;
    char* lB = (char*)sB;
    const int dW = wid << 10;

    auto stA = [&](int t, int kk) {
        const unsigned short* g = pa + (size_t)t * 64 + kk * 32;
        char* l = lA + ((t & 1) << 15) + (kk << 14) + dW;
        gload16(g, l);
        gload16(g + (size_t)128 * LD, l + 8192);
    };
    auto stB = [&](int t, int kk) {
        const unsigned short* g = pb + (size_t)t * 64 + kk * 32;
        char* l = lB + ((t & 1) << 15) + (kk << 14) + dW;
        gload16(g, l);
        gload16(g + (size_t)128 * LD, l + 8192);
    };

    stA(0, 0); stB(0, 0); stA(0, 1); stB(0, 1);
    asm volatile("s_waitcnt vmcnt(4)" ::: "memory");
    __builtin_amdgcn_s_barrier();

#pragma unroll 1
    for (int t = 0; t < NT; ++t) {
        const int sb = (t & 1) << 14;
        const unsigned short* A0 = sA + sb + aoff;
        const unsigned short* B0 = sB + sb + boff;
        const unsigned short* A1 = A0 + 8192;
        const unsigned short* B1 = B0 + 8192;
        const bool more = (t + 1 < NT);
        bf16x8 a[4], b[4];

        // ===== p0 =====
#pragma unroll
        for (int i = 0; i < 4; ++i) a[i] = *(const bf16x8*)(A0 + i * 512);
#pragma unroll
        for (int i = 0; i < 4; ++i) b[i] = *(const bf16x8*)(B0 + i * 512);
        if (more) stA(t + 1, 0);
        __builtin_amdgcn_s_barrier();
        asm volatile("s_waitcnt lgkmcnt(0)" ::: "memory");
        __builtin_amdgcn_sched_barrier(0);
        __builtin_amdgcn_s_setprio(1);
#pragma unroll
        for (int m = 0; m < 4; ++m)
#pragma unroll
            for (int n = 0; n < 4; ++n)
                acc[m][n] = mfma16(a[m], b[n], acc[m][n]);
        __builtin_amdgcn_s_setprio(0);
        __builtin_amdgcn_s_barrier();

        // ===== p1 =====
#pragma unroll
        for (int i = 0; i < 4; ++i)
            a[i] = *(const bf16x8*)(A0 + 2048 + i * 512);
        if (more) {
            stB(t + 1, 0);
            asm volatile("s_waitcnt vmcnt(4)" ::: "memory");
        } else {
            asm volatile("s_waitcnt vmcnt(0)" ::: "memory");
        }
        __builtin_amdgcn_s_barrier();
        asm volatile("s_waitcnt lgkmcnt(0)" ::: "memory");
        __builtin_amdgcn_sched_barrier(0);
        __builtin_amdgcn_s_setprio(1);
#pragma unroll
        for (int m = 0; m < 4; ++m)
#pragma unroll
            for (int n = 0; n < 4; ++n)
                acc[4 + m][n] = mfma16(a[m], b[n], acc[4 + m][n]);
        __builtin_amdgcn_s_setprio(0);
        __builtin_amdgcn_s_barrier();

        // ===== p2 =====
#pragma unroll
        for (int i = 0; i < 4; ++i) a[i] = *(const bf16x8*)(A1 + i * 512);
#pragma unroll
        for (int i = 0; i < 4; ++i) b[i] = *(const bf16x8*)(B1 + i * 512);
        if (more) stA(t + 1, 1);
        __builtin_amdgcn_s_barrier();
        asm volatile("s_waitcnt lgkmcnt(0)" ::: "memory");
        __builtin_amdgcn_sched_barrier(0);
        __builtin_amdgcn_s_setprio(1);
#pragma unroll
        for (int m = 0; m < 4; ++m)
#pragma unroll
            for (int n = 0; n < 4; ++n)
                acc[m][n] = mfma16(a[m], b[n], acc[m][n]);
        __builtin_amdgcn_s_setprio(0);
        __builtin_amdgcn_s_barrier();

        // ===== p3 =====
#pragma unroll
        for (int i = 0; i < 4; ++i)
            a[i] = *(const bf16x8*)(A1 + 2048 + i * 512);
        if (more) {
            stB(t + 1, 1);
            asm volatile("s_waitcnt vmcnt(4)" ::: "memory");
        }
        __builtin_amdgcn_s_barrier();
        asm volatile("s_waitcnt lgkmcnt(0)" ::: "memory");
        __builtin_amdgcn_sched_barrier(0);
        __builtin_amdgcn_s_setprio(1);
#pragma unroll
        for (int m = 0; m < 4; ++m)
#pragma unroll
            for (int n = 0; n < 4; ++n)
                acc[4 + m][n] = mfma16(a[m], b[n], acc[4 + m][n]);
        __builtin_amdgcn_s_setprio(0);
        __builtin_amdgcn_s_barrier();
    }
}

// ---------------- kernel 1: fused gate/up grouped GEMM + SwiGLU -----------
// A = xb (T x D), B = w13b[e] (2H x D interleave-16), h (T x H bf16).
// Optional fused w2 f32->bf16 convert (disjoint w2b region, R4-proven).
__global__ __launch_bounds__(512, 2) void k_gate_up(
    const unsigned short* __restrict__ xb,
    const unsigned short* __restrict__ w13b,
    const float* __restrict__ w2, unsigned short* __restrict__ w2b,
    const int* __restrict__ ntp, unsigned short* __restrict__ hbuf) {
    __shared__ unsigned short sA[2 * 2 * 8192];
    __shared__ unsigned short sB[2 * 2 * 8192];

    const int bid = blockIdx.x;
    const int tid = threadIdx.x;

    if (w2) {  // fused w2 convert: 32768 elems per block, then drain vmcnt
        const float* src = w2 + (size_t)bid * 32768;
        unsigned short* dst = w2b + (size_t)bid * 32768;
#pragma unroll
        for (int it = 0; it < 8; ++it) {
            int o = (it * 512 + tid) * 8;
            cvt8(src + o, dst + o);
        }
        asm volatile("s_waitcnt vmcnt(0)" ::: "memory");
    }

    // cluster mapping: XCD (bid&7) covers an 8tm x 4tn cluster window;
    // concurrent blocks share a small per-K-step L2 working set.
    const int tm = (bid & 7) * 8 + ((bid >> 3) & 7);
    const int tn = bid >> 6;  // 0..43

    const int row0 = tm << 8;
    const int e = expert_of_row(ntp, row0);
    const int lane = tid & 63, wid = tid >> 6;

    // staging sources: row = tid>>2, k-quarter = (tid&3)^((tid>>3)&3)
    const int sr = tid >> 2;
    const int sq = (tid & 3) ^ ((tid >> 3) & 3);
    const unsigned short* pa = xb + (size_t)(row0 + sr) * D + sq * 8;
    const unsigned short* pb = w13b + (size_t)e * (2 * H) * D +
                               (size_t)((tn << 8) + sr) * D + sq * 8;

    f32x4 acc[8][4] = {};
    gemm_4p<D, D / 64>(pa, pb, sA, sB, tid, acc);

    // Epilogue: ni pairs (0,1),(2,3) = (gate,up). C/D: col=lane&15,
    // row=(lane>>4)*4+j.
    const int wm = wid >> 2, wn = wid & 3;
    const int rbase = row0 + (wm << 7) + ((lane >> 4) << 2);
    const int cb = (((tn << 3) + (wn << 1)) << 4) + (lane & 15);
#pragma unroll
    for (int mi = 0; mi < 8; ++mi)
#pragma unroll
        for (int pi = 0; pi < 2; ++pi) {
            f32x4 g = acc[mi][2 * pi], u = acc[mi][2 * pi + 1];
            const int hcol = cb + (pi << 4);
#pragma unroll
            for (int j = 0; j < 4; ++j) {
                float gv = g[j];
                float hv = gv * u[j] / (1.f + __expf(-gv));
                hbuf[(size_t)(rbase + (mi << 4) + j) * H + hcol] = f2bf(hv);
            }
        }
}

// ---------------- kernel 2: down grouped GEMM -----------------------------
// A = h (T x H), B = w2b[e] (D x H), out (T x D f32). K = H = 5632.
// Expert-per-XCD cluster: XCD x owns tm in [8x,8x+8) (= expert x's 2048
// tokens) x tn in [0,8). A (h rows) and B (w2b[x]) each fetched by ONE
// XCD only; K-slice working set ~512KB fits L2.
__global__ __launch_bounds__(512, 2) void k_down(
    const unsigned short* __restrict__ hbuf,
    const unsigned short* __restrict__ w2b,
    const int* __restrict__ ntp,
    float* __restrict__ out) {
    __shared__ unsigned short sA[2 * 2 * 8192];
    __shared__ unsigned short sB[2 * 2 * 8192];

    const int bid = blockIdx.x;          // 512 blocks
    const int xcd = bid & 7;
    const int j = bid >> 3;              // 0..63
    const int tn = j & 7;
    const int tm = xcd * 8 + (j >> 3);   // 0..63, expert = xcd

    const int row0 = tm << 8;
    const int e = expert_of_row(ntp, row0);
    const int tid = threadIdx.x;
    const int lane = tid & 63, wid = tid >> 6;

    const int sr = tid >> 2;
    const int sq = (tid & 3) ^ ((tid >> 3) & 3);
    const unsigned short* pa = hbuf + (size_t)(row0 + sr) * H + sq * 8;
    const unsigned short* pb = w2b + (size_t)e * D * H +
                               (size_t)((tn << 8) + sr) * H + sq * 8;

    f32x4 acc[8][4] = {};
    gemm_4p<H, H / 64>(pa, pb, sA, sB, tid, acc);

    const int wm = wid >> 2, wn = wid & 3;
    const int rbase = row0 + (wm << 7) + ((lane >> 4) << 2);
    const int cb = (tn << 8) + (wn << 6) + (lane & 15);
#pragma unroll
    for (int mi = 0; mi < 8; ++mi)
#pragma unroll
        for (int ni = 0; ni < 4; ++ni) {
            f32x4 c = acc[mi][ni];
#pragma unroll
            for (int j2 = 0; j2 < 4; ++j2)
                out[(size_t)(rbase + (mi << 4) + j2) * D + cb + (ni << 4)] =
                    c[j2];
        }
}

extern "C" void kernel_launch(void* const* d_in, const int* in_sizes, int n_in,
                              void* d_out, int out_size, void* d_ws,
                              size_t ws_size, hipStream_t stream) {
    const float* x = (const float*)d_in[0];
    const float* w1 = (const float*)d_in[1];
    const float* w2 = (const float*)d_in[2];
    const float* w3 = (const float*)d_in[3];
    const int* ntp = (const int*)d_in[4];
    float* out = (float*)d_out;

    char* ws = (char*)d_ws;
    // ws layout (bytes):
    //   xb  : [0, 67108864)                       T*D*2
    //   w13b: [67108864, 436207616)               E*2H*D*2
    //   h   : [436207616, 620756992)              T*H*2
    //   w2b : [620756992, 805306368)  if ws fits  E*D*H*2 (else alias w13b)
    unsigned short* xb = (unsigned short*)(ws + 0);
    unsigned short* w13b = (unsigned short*)(ws + 67108864L);
    unsigned short* hbuf = (unsigned short*)(ws + 436207616L);
    const bool big = ws_size >= 805306368UL;
    unsigned short* w2b = big ? (unsigned short*)(ws + 620756992L) : w13b;

    k_cvt_pre<<<2048, 256, 0, stream>>>(x, w1, w3, xb, w13b);

    k_gate_up<<<(T / 256) * (2 * H / 256), 512, 0, stream>>>(
        xb, w13b, big ? w2 : nullptr, big ? w2b : nullptr, ntp, hbuf);

    if (!big)
        k_cvt<<<2048, 256, 0, stream>>>(w2, w2b, (long)E * D * H / 8);

    k_down<<<(T / 256) * (D / 256), 512, 0, stream>>>(hbuf, w2b, ntp, out);
}